// Round 1
// baseline (357.548 us; speedup 1.0000x reference)
//
#include <hip/hip_runtime.h>

// Cost volume: volume[b,d,h,w] = mean_c left[b,c,h,w] * right[b,c,h,w-d], 0 for w<d.
// B=8 C=64 H=160 W=320 D=48, f32 in / f32 out.
//
// One block per (b,h) row. Channel dim streamed through LDS in 4 chunks of 16,
// double-buffered (80 KB LDS -> 2 blocks/CU). global_load_lds width-16 staging.
// Each thread computes an 8x8 (d x w) output tile from registers.

constexpr int C_ = 64, H_ = 160, W_ = 320, D_ = 48;
constexpr int HW_ = H_ * W_;            // 51200
constexpr int CK_ = 16;                 // channels per LDS chunk
constexpr int CHF = CK_ * W_;           // 5120 floats per chunk buffer
// LDS layout (floats): [L0: 0..5120) [L1: 5120..10240) [R0: 10240..15360) [R1: 15360..20480)
// R-chunk reads may underflow by up to 48 floats (diagonal/below-diagonal tiles);
// those land in the preceding buffer (valid LDS) and only feed masked-out outputs.

typedef __attribute__((address_space(1))) unsigned int gu32;
typedef __attribute__((address_space(3))) unsigned int lu32;

__device__ __forceinline__ void gload_lds16(const float* g, float* l) {
  // async global->LDS, 16 bytes per lane; LDS dest = wave-uniform base + lane*16
  __builtin_amdgcn_global_load_lds((const gu32*)g, (lu32*)l, 16, 0, 0);
}

__global__ __launch_bounds__(256, 2)
void corvol_kernel(const float* __restrict__ L, const float* __restrict__ R,
                   float* __restrict__ out) {
  __shared__ __align__(16) float lds[4 * CHF];   // 81920 B

  const int tid  = threadIdx.x;
  const int lane = tid & 63;
  const int wv   = tid >> 6;

  const int bh = blockIdx.x;            // b*H + h
  const int b  = bh / H_;
  const int h  = bh - b * H_;
  const int inbase = b * (C_ * HW_) + h * W_;
  const float* Lbh = L + inbase;
  const float* Rbh = R + inbase;

  // thread -> (d-tile, w-tile). 40 w-tiles x 6 d-tiles = 240 active threads.
  const int wt = tid % 40;
  const int dt = tid / 40;
  const int w0 = wt * 8;
  const int d0 = dt * 8;
  const bool active = (dt < 6);

  float acc[8][8];
#pragma unroll
  for (int i = 0; i < 8; ++i)
#pragma unroll
    for (int j = 0; j < 8; ++j) acc[i][j] = 0.0f;

  auto stage = [&](int ck, int p) {
    const int c0 = ck * CK_;
    // 20 segments of 1024 B per matrix; wave wv does segments wv, wv+4, ...
#pragma unroll
    for (int s = 0; s < 5; ++s) {
      const int seg = wv + s * 4;              // 0..19 (wave-uniform)
      const int f = seg * 256 + lane * 4;      // float index within [16][320] chunk
      const int c = f / W_;                    // 0..15 (lane 16B never straddles a row: 320%4==0)
      const int w = f - c * W_;
      const int goff = (c0 + c) * HW_ + w;
      gload_lds16(Lbh + goff, &lds[p * CHF + seg * 256]);
      gload_lds16(Rbh + goff, &lds[2 * CHF + p * CHF + seg * 256]);
    }
  };

  auto compute = [&](int p) {
    const float* Lc = &lds[p * CHF];
    const float* Rc = &lds[2 * CHF + p * CHF];
#pragma unroll
    for (int c = 0; c < CK_; ++c) {
      const float4 a0 = *(const float4*)(Lc + c * W_ + w0);
      const float4 a1 = *(const float4*)(Lc + c * W_ + w0 + 4);
      const int rb = c * W_ + (w0 - d0 - 8);   // may be negative only for masked tiles
      const float4 r0 = *(const float4*)(Rc + rb);
      const float4 r1 = *(const float4*)(Rc + rb + 4);
      const float4 r2 = *(const float4*)(Rc + rb + 8);
      const float4 r3 = *(const float4*)(Rc + rb + 12);
      const float la[8] = {a0.x, a0.y, a0.z, a0.w, a1.x, a1.y, a1.z, a1.w};
      const float rv[16] = {r0.x, r0.y, r0.z, r0.w, r1.x, r1.y, r1.z, r1.w,
                            r2.x, r2.y, r2.z, r2.w, r3.x, r3.y, r3.z, r3.w};
#pragma unroll
      for (int di = 0; di < 8; ++di)
#pragma unroll
        for (int wi = 0; wi < 8; ++wi)
          acc[di][wi] = fmaf(la[wi], rv[8 + wi - di], acc[di][wi]);
    }
  };

  stage(0, 0);
  __syncthreads();

#pragma unroll 1
  for (int ck = 0; ck < 4; ++ck) {
    if (ck < 3) stage(ck + 1, (ck + 1) & 1);   // prefetch next chunk
    if (active) compute(ck & 1);
    __syncthreads();                            // drains vmcnt before buffer reuse
  }

  if (active) {
    constexpr float sc = 1.0f / 64.0f;
    const int ob = b * (D_ * HW_) + h * W_ + w0;
#pragma unroll
    for (int di = 0; di < 8; ++di) {
      const int d = d0 + di;
      float4 o0, o1;
      o0.x = (w0 + 0 >= d) ? acc[di][0] * sc : 0.0f;
      o0.y = (w0 + 1 >= d) ? acc[di][1] * sc : 0.0f;
      o0.z = (w0 + 2 >= d) ? acc[di][2] * sc : 0.0f;
      o0.w = (w0 + 3 >= d) ? acc[di][3] * sc : 0.0f;
      o1.x = (w0 + 4 >= d) ? acc[di][4] * sc : 0.0f;
      o1.y = (w0 + 5 >= d) ? acc[di][5] * sc : 0.0f;
      o1.z = (w0 + 6 >= d) ? acc[di][6] * sc : 0.0f;
      o1.w = (w0 + 7 >= d) ? acc[di][7] * sc : 0.0f;
      *(float4*)(out + ob + d * HW_)     = o0;
      *(float4*)(out + ob + d * HW_ + 4) = o1;
    }
  }
}

extern "C" void kernel_launch(void* const* d_in, const int* in_sizes, int n_in,
                              void* d_out, int out_size, void* d_ws, size_t ws_size,
                              hipStream_t stream) {
  const float* left  = (const float*)d_in[0];
  const float* right = (const float*)d_in[1];
  float* out = (float*)d_out;
  const int B = 8;
  dim3 grid(B * H_), block(256);
  corvol_kernel<<<grid, block, 0, stream>>>(left, right, out);
}